// Round 21
// baseline (1362.358 us; speedup 1.0000x reference)
//
#include <hip/hip_runtime.h>

#define NN   729
#define NF   730   // N+1
#define BV   8
#define KK   32
#define NBAS 40
#define MAXIT 10
#define PI_F 3.14159265358979323846f

#define MTH   512   // mix threads (8 waves)
#define BT    32    // steps per block (MFMA K=32 full)
#define AST   448   // padded max active rows
#define NMT   28    // m-tiles (448/16)
#define NPB   14    // max 32-row blocks (448/32)

typedef short v8s __attribute__((ext_vector_type(8)));
typedef float v4f __attribute__((ext_vector_type(4)));

__device__ __forceinline__ unsigned short f2bf(float f) {
    unsigned int x = __float_as_uint(f);
    unsigned int r = x + 0x7FFFu + ((x >> 16) & 1u);   // RNE bf16
    return (unsigned short)(r >> 16);
}

// ---------------- build Ct (730x730), Ct[i][j] = C[j][i] ----------------
__global__ void build_C_kernel(const float* __restrict__ coeff,
                               const float* __restrict__ upper,
                               const float* __restrict__ basis,
                               float* __restrict__ Ct) {
    int idx = blockIdx.x * blockDim.x + threadIdx.x;
    if (idx >= NF * NF) return;
    int i = idx / NF, j = idx - i * NF;
    float val;
    if (i == 0) {
        val = (j == 0) ? 0.f : upper[j - 1];
    } else if (j == 0) {
        val = upper[i - 1];
    } else {
        float acc = 0.f;
        const float* bp = basis + (size_t)(i - 1) * NN + (j - 1);
        #pragma unroll 8
        for (int b = 0; b < NBAS; ++b)
            acc = fmaf(coeff[b], bp[(size_t)b * NN * NN], acc);
        val = acc;
    }
    Ct[(size_t)j * NF + i] = val;
}

// ---------------- init V  (B x 730 x 32) ----------------
__global__ void init_V_kernel(const float* __restrict__ z,
                              const float* __restrict__ vraw,
                              float* __restrict__ V) {
    int g = threadIdx.x >> 5;
    int k = threadIdx.x & 31;
    int row = blockIdx.x * 8 + g;           // 0..5839
    int b = row / NF, n = row - b * NF;
    const float* vr = vraw + (size_t)b * NF * KK;

    float v0 = vr[k];
    float s2 = v0 * v0;
    #pragma unroll
    for (int off = 16; off; off >>= 1) s2 += __shfl_xor(s2, off, 32);
    v0 = v0 / sqrtf(s2);

    float vn = vr[(size_t)n * KK + k];
    float d = vn * v0;
    #pragma unroll
    for (int off = 16; off; off >>= 1) d += __shfl_xor(d, off, 32);
    float u = vn - d * v0;
    float un2 = u * u;
    #pragma unroll
    for (int off = 16; off; off >>= 1) un2 += __shfl_xor(un2, off, 32);
    u = u / fmaxf(sqrtf(un2), 1e-8f);

    float zf = (n == 0) ? 1.f : z[b * NN + (n - 1)];
    float c = cosf(PI_F * zf), s = sinf(PI_F * zf);
    float outv = -c * v0 + s * u;
    if (n == 0) outv = v0;
    V[((size_t)b * NF + n) * KK + k] = outv;
}

// ---------------- build per-batch active lists (perm order) ----------------
__global__ void build_act_kernel(const int* __restrict__ is_input,
                                 const int* __restrict__ perm,
                                 int* __restrict__ act, int* __restrict__ nA_arr) {
    int b = blockIdx.x, l = threadIdx.x;   // 64 threads = 1 wave
    int base = 0;
    for (int c = 0; c < (NN + 63) / 64; ++c) {
        int idx = c * 64 + l;
        bool f = false; int pi = 0;
        if (idx < NN) { pi = perm[idx]; f = (is_input[b * NN + pi - 1] == 0); }
        unsigned long long m = __ballot(f);
        int pos = __popcll(m & ((1ull << l) - 1ull));
        if (f && base + pos < AST) act[b * AST + base + pos] = pi;
        base += __popcll(m);
    }
    if (base > AST) base = AST;
    if (l == 0) nA_arr[b] = base;
    for (int p = base + l; p < AST; p += 64) act[b * AST + p] = 0;
}

// --- init W compact + compact V copy ---
__global__ void init_W_kernel(const float* __restrict__ Ct,
                              const int* __restrict__ act,
                              const int* __restrict__ nA_arr,
                              const float* __restrict__ V,
                              float* __restrict__ Wc,
                              float* __restrict__ Vact) {
    int b = blockIdx.y;
    int a = blockIdx.x * 8 + (threadIdx.x >> 5);
    int k = threadIdx.x & 31;
    int nA = nA_arr[b];
    float w = 0.f;
    int ra = act[b * AST + a];
    float vv = V[((size_t)b * NF + ra) * KK + k];
    if (a < nA) {
        const float* ctr = Ct + (size_t)ra * NF;
        const float* vb = V + (size_t)b * NF * KK + k;
        float acc = 0.f;
        for (int j = 0; j < NF; ++j)
            acc = fmaf(ctr[j], vb[(size_t)j * KK], acc);
        w = acc - ctr[ra] * vv;
    }
    Wc[((size_t)b * AST + a) * KK + k] = w;
    Vact[((size_t)b * AST + a) * KK + k] = vv;
}

// --- prepack A fragments (bf16), full K=32:
//     A[m=mt*16+row][k] = C[r_{pb*32+k}][r_m] = Ct[r_m][r_{pb*32+k}]
//     Fragment: lane l (0..63): row=l&15, k=(l>>4)*8+i. ---
__global__ void prepack_A_kernel(const float* __restrict__ Ct,
                                 const int* __restrict__ act,
                                 v8s* __restrict__ Apack) {
    int b = blockIdx.y, pm = blockIdx.x;      // pm = pb*NMT + mt
    int pb = pm / NMT, mt = pm - NMT * pb;
    int l = threadIdx.x;                      // 64
    int row = mt * 16 + (l & 15);
    int ra = act[b * AST + row];
    const float* crow = Ct + (size_t)ra * NF;
    v8s v;
    #pragma unroll
    for (int i = 0; i < 8; ++i) {
        int k = (l >> 4) * 8 + i;             // 0..31
        int rt = act[b * AST + pb * 32 + k];
        v[i] = (short)f2bf(crow[rt]);
    }
    Apack[(((size_t)b * NPB + pb) * NMT + mt) * 64 + l] = v;
}

// 16-lane row sum via DPP row rotations (pure VALU)
__device__ __forceinline__ float rowsum16(float x) {
    int y;
    y = __builtin_amdgcn_update_dpp(0, __float_as_int(x), 0x121, 0xF, 0xF, false);
    x += __int_as_float(y);
    y = __builtin_amdgcn_update_dpp(0, __float_as_int(x), 0x122, 0xF, 0xF, false);
    x += __int_as_float(y);
    y = __builtin_amdgcn_update_dpp(0, __float_as_int(x), 0x124, 0xF, 0xF, false);
    x += __int_as_float(y);
    y = __builtin_amdgcn_update_dpp(0, __float_as_int(x), 0x128, 0xF, 0xF, false);
    x += __int_as_float(y);
    return x;
}

// -- mixing: BT=32; bulk = MFMA rank-32 (full K); serial 32-step chain --
__global__ __launch_bounds__(MTH, 2)
void mix_kernel(const v8s* __restrict__ Apack_g,
                const float* __restrict__ Ct_g,
                const float* __restrict__ Wc_g,
                const float* __restrict__ Vact_g,
                const int* __restrict__ act_g,
                const int* __restrict__ nA_arr,
                const int* __restrict__ is_input,
                const float* __restrict__ z,
                const float* __restrict__ Vg,
                float* __restrict__ out) {
    __shared__ __align__(16) float V_c[AST * KK];       // 57344 B
    __shared__ __align__(16) float dv_s[2][BT * KK];    // 8192 B
    __shared__ __align__(16) float gpub[2][BT * KK];    // 8192 B
    __shared__ __align__(16) float cblk_s[2][BT * BT];  // 8192 B
    __shared__ __align__(16) float cmini_s[BT * BT];    // 4096 B
    __shared__ float Cd_s[AST];                         // 1792 B
    __shared__ int   slot_s[NF];                        // 2920 B
    __shared__ int   act_s[AST];                        // 1792 B  -> ~92 KB

    int b = blockIdx.x, tid = threadIdx.x;
    const v8s* Apack = Apack_g + ((size_t)b * NPB * NMT) * 64;
    const float* Vact = Vact_g + (size_t)b * AST * KK;
    int nA = nA_arr[b];
    int nblkp = (nA + BT - 1) / BT;
    if (nblkp < 2) nblkp = 2;
    if (nblkp > NPB) nblkp = NPB;
    int totB = MAXIT * nblkp;

    int wid = tid >> 6;
    int l64 = tid & 63;
    int col = l64 & 15, rg = l64 >> 4;    // MFMA fragment coords (rg 0..3)
    int k32 = tid & 31;                   // serial k

    // ---- setup ----
    if (tid < AST) act_s[tid] = act_g[b * AST + tid];
    __syncthreads();
    for (int idx = tid; idx < AST * 8; idx += MTH)
        ((float4*)V_c)[idx] = ((const float4*)Vact)[idx];
    if (tid < AST) Cd_s[tid] = Ct_g[(size_t)act_s[tid] * NF + act_s[tid]];
    if (tid < nA) slot_s[act_s[tid]] = tid;
    for (int idx = tid; idx < BT * BT; idx += MTH) {  // cblk block 0: [x][y]=C[r_x][r_y]
        int x = idx >> 5, y = idx & 31;
        cblk_s[0][idx] = Ct_g[(size_t)act_s[y] * NF + act_s[x]];
    }
    // W accumulators, MFMA C/D layout: acc[tl][nt][i] = W[mt*16+rg*4+i][nt*16+col]
    v4f acc[4][2];
    #pragma unroll
    for (int tl = 0; tl < 4; ++tl)
        #pragma unroll
        for (int nt = 0; nt < 2; ++nt) {
            v4f z4 = {0.f, 0.f, 0.f, 0.f};
            acc[tl][nt] = z4;
        }
    if (wid >= 1) {
        #pragma unroll
        for (int tl = 0; tl < 4; ++tl) {
            int mt = (wid - 1) * 4 + tl;
            #pragma unroll
            for (int nt = 0; nt < 2; ++nt)
                #pragma unroll
                for (int i = 0; i < 4; ++i)
                    acc[tl][nt][i] =
                        Wc_g[((size_t)b * AST + mt * 16 + rg * 4 + i) * KK + nt * 16 + col];
        }
        if (wid == 1) {   // publish block 0 (mt 0,1) raw into gpub[1]
            #pragma unroll
            for (int tl = 0; tl < 2; ++tl)
                #pragma unroll
                for (int nt = 0; nt < 2; ++nt)
                    #pragma unroll
                    for (int i = 0; i < 4; ++i)
                        gpub[1][(tl * 16 + rg * 4 + i) * KK + nt * 16 + col] = acc[tl][nt][i];
        }
    }
    __syncthreads();

    for (int bi = 0; bi < totB; ++bi) {
        int blk = bi % nblkp, s0 = blk * BT;
        int pblk = (bi - 1 + nblkp) % nblkp, sp0 = pblk * BT;  // junk at bi=0
        int cb = bi & 1, pv = cb ^ 1;
        int nblk2 = (bi + 1) % nblkp, sn0 = nblk2 * BT;

        // ================= Region 1 =================
        if (wid == 0) {
            // ---- serial: 32-step chain, 1 float/lane, vo as 1-deep ring ----
            __builtin_amdgcn_s_setprio(1);
            float g[BT];
            #pragma unroll
            for (int u = 0; u < BT; ++u)
                g[u] = gpub[pv][u * KK + k32];
            float vo = V_c[s0 * KK + k32];
            #pragma unroll
            for (int u = 0; u < BT; ++u) {
                int s = s0 + u;
                float von = (u + 1 < BT) ? V_c[(s + 1) * KK + k32] : 0.f;  // prefetch
                float n2 = g[u] * g[u];
                n2 = rowsum16(n2);
                n2 += __shfl_xor(n2, 16, 32);
                float inv = -__builtin_amdgcn_rsqf(fmaxf(n2, 1e-16f));
                float msk = (s < nA) ? 1.f : 0.f;
                float d = fmaf(g[u], inv, -vo) * msk;
                if (tid < 32) {
                    dv_s[cb][u * KK + k32] = d;
                    V_c[s * KK + k32] = vo + d;
                }
                #pragma unroll
                for (int u2 = u + 1; u2 < BT; ++u2)
                    g[u2] = fmaf(cblk_s[cb][u * BT + u2], d, g[u2]);
                vo = von;
            }
            __builtin_amdgcn_s_setprio(0);
        } else {
            // staging (scalar gathers from Ct via act_s; off critical path)
            if (wid == 6) {   // cmini[u*32+t] = C[r_{s0+t}][r_{sn0+u}]
                for (int idx = l64; idx < BT * BT; idx += 64) {
                    int u = idx >> 5, t = idx & 31;
                    cmini_s[idx] =
                        Ct_g[(size_t)act_s[sn0 + u] * NF + act_s[s0 + t]];
                }
            }
            if (wid == 7) {   // cblk[pv][x*32+y] = C[r_{sn0+x}][r_{sn0+y}]
                for (int idx = l64; idx < BT * BT; idx += 64) {
                    int x = idx >> 5, y = idx & 31;
                    cblk_s[pv][idx] =
                        Ct_g[(size_t)act_s[sn0 + y] * NF + act_s[sn0 + x]];
                }
            }
            // ---- bulk: rank-32 via MFMA (full K=32) ----
            if (bi > 0) {
                v8s bf0, bf1;
                #pragma unroll
                for (int i = 0; i < 8; ++i) {
                    int t = rg * 8 + i;           // k = 0..31 across 64 lanes
                    bf0[i] = (short)f2bf(dv_s[pv][t * KK + col]);
                    bf1[i] = (short)f2bf(dv_s[pv][t * KK + 16 + col]);
                }
                #pragma unroll
                for (int tl = 0; tl < 4; ++tl) {
                    int mt = (wid - 1) * 4 + tl;
                    v8s af = Apack[((size_t)pblk * NMT + mt) * 64 + l64];
                    acc[tl][0] = __builtin_amdgcn_mfma_f32_16x16x32_bf16(af, bf0, acc[tl][0], 0, 0, 0);
                    acc[tl][1] = __builtin_amdgcn_mfma_f32_16x16x32_bf16(af, bf1, acc[tl][1], 0, 0, 0);
                }
                // diag self-cancel for rows of the previous block (fp32 exact)
                #pragma unroll
                for (int tl = 0; tl < 4; ++tl) {
                    int mt = (wid - 1) * 4 + tl;
                    if ((mt >> 1) == pblk) {
                        #pragma unroll
                        for (int i = 0; i < 4; ++i) {
                            int rb = (mt & 1) * 16 + rg * 4 + i;   // row within block
                            float cd = Cd_s[mt * 16 + rg * 4 + i];
                            acc[tl][0][i] = fmaf(-cd, dv_s[pv][rb * KK + col],      acc[tl][0][i]);
                            acc[tl][1][i] = fmaf(-cd, dv_s[pv][rb * KK + 16 + col], acc[tl][1][i]);
                        }
                    }
                }
            }
            // ---- publish next block's raw rows (fold happens in R2) ----
            #pragma unroll
            for (int tl = 0; tl < 4; ++tl) {
                int mt = (wid - 1) * 4 + tl;
                if ((mt >> 1) == nblk2) {
                    int rb0 = (mt & 1) * 16;
                    #pragma unroll
                    for (int i = 0; i < 4; ++i) {
                        gpub[cb][(rb0 + rg * 4 + i) * KK + col]      = acc[tl][0][i];
                        gpub[cb][(rb0 + rg * 4 + i) * KK + 16 + col] = acc[tl][1][i];
                    }
                }
            }
        }
        __syncthreads();

        // ===== Region 2: cooperative fold gpub[cb] += cmini * dv(bi) =====
        {
            int k = tid & 31;
            int u0 = tid >> 5;   // 0..15
            #pragma unroll
            for (int uu = 0; uu < 2; ++uu) {
                int u = u0 + 16 * uu;
                float g = gpub[cb][u * KK + k];
                #pragma unroll
                for (int t = 0; t < BT; ++t)
                    g = fmaf(cmini_s[u * BT + t], dv_s[cb][t * KK + k], g);
                gpub[cb][u * KK + k] = g;
            }
        }
        __syncthreads();
    }

    // ---- epilogue: z_out ----
    int k = tid & 31, r = tid >> 5;   // r in 0..15
    float v0k = Vg[(size_t)b * NF * KK + k];
    for (int n = 1 + r; n <= NN; n += 16) {
        int ii = is_input[b * NN + n - 1];
        float res;
        if (ii == 1) {
            res = z[b * NN + n - 1];
        } else {
            int a = slot_s[n];
            float dot = V_c[a * KK + k] * v0k;
            #pragma unroll
            for (int off = 16; off; off >>= 1) dot += __shfl_xor(dot, off, 32);
            float ca = fminf(fmaxf(-dot, -1.f + 1e-6f), 1.f - 1e-6f);
            res = acosf(ca) * (1.f / PI_F);
        }
        if (k == 0) out[b * NN + n - 1] = res;
    }
}

extern "C" void kernel_launch(void* const* d_in, const int* in_sizes, int n_in,
                              void* d_out, int out_size, void* d_ws, size_t ws_size,
                              hipStream_t stream) {
    const float* coeff    = (const float*)d_in[0];
    const float* upper    = (const float*)d_in[1];
    const float* basis    = (const float*)d_in[2];
    const float* z        = (const float*)d_in[3];
    const int*   is_input = (const int*)d_in[4];
    const float* vraw     = (const float*)d_in[5];
    const int*   perm     = (const int*)d_in[6];
    float* out = (float*)d_out;

    float* ws   = (float*)d_ws;
    float* Ct   = ws;                              // 730*730
    float* V    = Ct + (size_t)NF * NF;            // 8*730*32
    float* Wc   = V + (size_t)BV * NF * KK;        // 8*448*32
    float* Vact = Wc + (size_t)BV * AST * KK;      // 8*448*32
    int*   act  = (int*)(Vact + (size_t)BV * AST * KK);  // 8*448
    int*   nAa  = act + BV * AST;                  // 8
    v8s*  Apack = (v8s*)(nAa + 8);                 // 8*14*28*64 v8s = 3.2 MB
    // total ws ≈ 7.1 MB

    build_C_kernel<<<dim3((NF * NF + 255) / 256), dim3(256), 0, stream>>>(coeff, upper, basis, Ct);
    init_V_kernel<<<dim3(730), dim3(256), 0, stream>>>(z, vraw, V);
    build_act_kernel<<<dim3(BV), dim3(64), 0, stream>>>(is_input, perm, act, nAa);
    init_W_kernel<<<dim3(AST / 8, BV), dim3(256), 0, stream>>>(Ct, act, nAa, V, Wc, Vact);
    prepack_A_kernel<<<dim3(NPB * NMT, BV), dim3(64), 0, stream>>>(Ct, act, Apack);
    mix_kernel<<<dim3(BV), dim3(MTH), 0, stream>>>(Apack, Ct, Wc, Vact, act, nAa, is_input, z, V, out);
}

// Round 22
// 896.221 us; speedup vs baseline: 1.5201x; 1.5201x over previous
//
#include <hip/hip_runtime.h>

#define NN   729
#define NF   730   // N+1
#define BV   8
#define KK   32
#define NBAS 40
#define MAXIT 10
#define PI_F 3.14159265358979323846f

#define MTH   512   // mix threads (8 waves)
#define BT    16    // steps per block
#define AST   448   // padded max active rows
#define NMT   28    // m-tiles (448/16)

typedef short v8s __attribute__((ext_vector_type(8)));
typedef float v4f __attribute__((ext_vector_type(4)));

__device__ __forceinline__ unsigned short f2bf(float f) {
    unsigned int x = __float_as_uint(f);
    unsigned int r = x + 0x7FFFu + ((x >> 16) & 1u);   // RNE bf16
    return (unsigned short)(r >> 16);
}

// ---------------- build Ct (730x730), Ct[i][j] = C[j][i] ----------------
__global__ void build_C_kernel(const float* __restrict__ coeff,
                               const float* __restrict__ upper,
                               const float* __restrict__ basis,
                               float* __restrict__ Ct) {
    int idx = blockIdx.x * blockDim.x + threadIdx.x;
    if (idx >= NF * NF) return;
    int i = idx / NF, j = idx - i * NF;
    float val;
    if (i == 0) {
        val = (j == 0) ? 0.f : upper[j - 1];
    } else if (j == 0) {
        val = upper[i - 1];
    } else {
        float acc = 0.f;
        const float* bp = basis + (size_t)(i - 1) * NN + (j - 1);
        #pragma unroll 8
        for (int b = 0; b < NBAS; ++b)
            acc = fmaf(coeff[b], bp[(size_t)b * NN * NN], acc);
        val = acc;
    }
    Ct[(size_t)j * NF + i] = val;
}

// ---------------- init V  (B x 730 x 32) ----------------
__global__ void init_V_kernel(const float* __restrict__ z,
                              const float* __restrict__ vraw,
                              float* __restrict__ V) {
    int g = threadIdx.x >> 5;
    int k = threadIdx.x & 31;
    int row = blockIdx.x * 8 + g;           // 0..5839
    int b = row / NF, n = row - b * NF;
    const float* vr = vraw + (size_t)b * NF * KK;

    float v0 = vr[k];
    float s2 = v0 * v0;
    #pragma unroll
    for (int off = 16; off; off >>= 1) s2 += __shfl_xor(s2, off, 32);
    v0 = v0 / sqrtf(s2);

    float vn = vr[(size_t)n * KK + k];
    float d = vn * v0;
    #pragma unroll
    for (int off = 16; off; off >>= 1) d += __shfl_xor(d, off, 32);
    float u = vn - d * v0;
    float un2 = u * u;
    #pragma unroll
    for (int off = 16; off; off >>= 1) un2 += __shfl_xor(un2, off, 32);
    u = u / fmaxf(sqrtf(un2), 1e-8f);

    float zf = (n == 0) ? 1.f : z[b * NN + (n - 1)];
    float c = cosf(PI_F * zf), s = sinf(PI_F * zf);
    float outv = -c * v0 + s * u;
    if (n == 0) outv = v0;
    V[((size_t)b * NF + n) * KK + k] = outv;
}

// ---------------- build per-batch active lists (perm order) ----------------
__global__ void build_act_kernel(const int* __restrict__ is_input,
                                 const int* __restrict__ perm,
                                 int* __restrict__ act, int* __restrict__ nA_arr) {
    int b = blockIdx.x, l = threadIdx.x;   // 64 threads = 1 wave
    int base = 0;
    for (int c = 0; c < (NN + 63) / 64; ++c) {
        int idx = c * 64 + l;
        bool f = false; int pi = 0;
        if (idx < NN) { pi = perm[idx]; f = (is_input[b * NN + pi - 1] == 0); }
        unsigned long long m = __ballot(f);
        int pos = __popcll(m & ((1ull << l) - 1ull));
        if (f && base + pos < AST) act[b * AST + base + pos] = pi;
        base += __popcll(m);
    }
    if (base > AST) base = AST;
    if (l == 0) nA_arr[b] = base;
    for (int p = base + l; p < AST; p += 64) act[b * AST + p] = 0;
}

// --- init W compact + compact V copy ---
__global__ void init_W_kernel(const float* __restrict__ Ct,
                              const int* __restrict__ act,
                              const int* __restrict__ nA_arr,
                              const float* __restrict__ V,
                              float* __restrict__ Wc,
                              float* __restrict__ Vact) {
    int b = blockIdx.y;
    int a = blockIdx.x * 8 + (threadIdx.x >> 5);
    int k = threadIdx.x & 31;
    int nA = nA_arr[b];
    float w = 0.f;
    int ra = act[b * AST + a];
    float vv = V[((size_t)b * NF + ra) * KK + k];
    if (a < nA) {
        const float* ctr = Ct + (size_t)ra * NF;
        const float* vb = V + (size_t)b * NF * KK + k;
        float acc = 0.f;
        for (int j = 0; j < NF; ++j)
            acc = fmaf(ctr[j], vb[(size_t)j * KK], acc);
        w = acc - ctr[ra] * vv;
    }
    Wc[((size_t)b * AST + a) * KK + k] = w;
    Vact[((size_t)b * AST + a) * KK + k] = vv;
}

// --- prepack A fragments (bf16): A[row][t] = C[r_{pb*16+t}][r_{mt*16+row}]
//     = Ct[r_row][r_t]. Fragment: lane l (0..31): row=l&15, k=(l>>4)*8+i. ---
__global__ void prepack_A_kernel(const float* __restrict__ Ct,
                                 const int* __restrict__ act,
                                 v8s* __restrict__ Apack) {
    int b = blockIdx.y, pm = blockIdx.x;      // pm = pb*NMT + mt
    int pb = pm / NMT, mt = pm - NMT * pb;
    int l = threadIdx.x;                      // 64
    if (l >= 32) return;
    int row = mt * 16 + (l & 15);
    int ra = act[b * AST + row];
    const float* crow = Ct + (size_t)ra * NF;
    v8s v;
    #pragma unroll
    for (int i = 0; i < 8; ++i) {
        int t = (l >> 4) * 8 + i;             // 0..15 (l>>4 in {0,1})
        int rt = act[b * AST + pb * 16 + t];
        v[i] = (short)f2bf(crow[rt]);
    }
    Apack[(((size_t)b * NMT + pb) * NMT + mt) * 32 + l] = v;
}

// 16-lane row sum via DPP row rotations (pure VALU)
__device__ __forceinline__ float rowsum16(float x) {
    int y;
    y = __builtin_amdgcn_update_dpp(0, __float_as_int(x), 0x121, 0xF, 0xF, false);
    x += __int_as_float(y);
    y = __builtin_amdgcn_update_dpp(0, __float_as_int(x), 0x122, 0xF, 0xF, false);
    x += __int_as_float(y);
    y = __builtin_amdgcn_update_dpp(0, __float_as_int(x), 0x124, 0xF, 0xF, false);
    x += __int_as_float(y);
    y = __builtin_amdgcn_update_dpp(0, __float_as_int(x), 0x128, 0xF, 0xF, false);
    x += __int_as_float(y);
    return x;
}

// -- mixing: ONE barrier/iter; serial interleaves the cmini fold per-step --
__global__ __launch_bounds__(MTH, 2)
void mix_kernel(const v8s* __restrict__ Apack_g,
                const float* __restrict__ Ct_g,
                const float* __restrict__ Wc_g,
                const float* __restrict__ Vact_g,
                const int* __restrict__ act_g,
                const int* __restrict__ nA_arr,
                const int* __restrict__ is_input,
                const float* __restrict__ z,
                const float* __restrict__ Vg,
                float* __restrict__ out) {
    __shared__ __align__(16) float V_c[AST * KK];        // 57344 B
    __shared__ __align__(16) float dv_s[2][BT * KK];     // 4096 B
    __shared__ __align__(16) float gpub[2][BT * KK];     // 4096 B
    __shared__ __align__(16) float cblk_s[2][BT * BT];   // 2048 B
    __shared__ __align__(16) float cmini_s[2][BT * BT];  // 2048 B
    __shared__ float Cd_s[AST];                          // 1792 B
    __shared__ int   slot_s[NF];                         // 2920 B
    __shared__ int   act_s[AST];                         // 1792 B

    int b = blockIdx.x, tid = threadIdx.x;
    const v8s* Apack = Apack_g + ((size_t)b * NMT * NMT) * 32;
    const float* Vact = Vact_g + (size_t)b * AST * KK;
    int nA = nA_arr[b];
    int nblkp = (nA + BT - 1) / BT;
    if (nblkp < 2) nblkp = 2;
    if (nblkp > NMT) nblkp = NMT;
    int totB = MAXIT * nblkp;

    int wid = tid >> 6;
    int l64 = tid & 63;
    int col = l64 & 15, rg = l64 >> 4;    // MFMA fragment coords
    int k32 = tid & 31;                   // serial k

    // ---- setup ----
    if (tid < AST) act_s[tid] = act_g[b * AST + tid];
    __syncthreads();
    for (int idx = tid; idx < AST * 8; idx += MTH)
        ((float4*)V_c)[idx] = ((const float4*)Vact)[idx];
    if (tid < AST) Cd_s[tid] = Ct_g[(size_t)act_s[tid] * NF + act_s[tid]];
    if (tid < nA) slot_s[act_s[tid]] = tid;
    if (tid < 256) {   // cblk for block 0: cblk[t*16+u] = C[r_t][r_u] = Ct[r_u][r_t]
        int t = tid >> 4, u = tid & 15;
        cblk_s[0][t * BT + u] = Ct_g[(size_t)act_s[u] * NF + act_s[t]];
    }
    // W accumulators in MFMA C/D layout: acc[tl][nt][i] = W[mt*16+rg*4+i][nt*16+col]
    v4f acc[4][2];
    #pragma unroll
    for (int tl = 0; tl < 4; ++tl)
        #pragma unroll
        for (int nt = 0; nt < 2; ++nt) {
            v4f z4 = {0.f, 0.f, 0.f, 0.f};
            acc[tl][nt] = z4;
        }
    if (wid >= 1) {
        #pragma unroll
        for (int tl = 0; tl < 4; ++tl) {
            int mt = (wid - 1) * 4 + tl;
            #pragma unroll
            for (int nt = 0; nt < 2; ++nt)
                #pragma unroll
                for (int i = 0; i < 4; ++i)
                    acc[tl][nt][i] =
                        Wc_g[((size_t)b * AST + mt * 16 + rg * 4 + i) * KK + nt * 16 + col];
        }
        if (wid == 1) {   // publish tile 0 raw into gpub[1] (pv at bi=0)
            #pragma unroll
            for (int nt = 0; nt < 2; ++nt)
                #pragma unroll
                for (int i = 0; i < 4; ++i)
                    gpub[1][(rg * 4 + i) * KK + nt * 16 + col] = acc[0][nt][i];
        }
    }
    __syncthreads();

    for (int bi = 0; bi < totB; ++bi) {
        int blk = bi % nblkp, s0 = blk * BT;
        int pblk = (bi - 1 + nblkp) % nblkp, sp0 = pblk * BT;  // junk at bi=0
        int cb = bi & 1, pv = cb ^ 1;
        int nblk2 = (bi + 1) % nblkp, sn0 = nblk2 * BT;

        // ================= single region =================
        if (wid == 0) {
            // ---- serial: 16-step chain; fold dv(bi-1) interleaved per-step ----
            __builtin_amdgcn_s_setprio(1);
            float g[BT], dvp[BT];
            #pragma unroll
            for (int u = 0; u < BT; ++u)
                g[u] = gpub[pv][u * KK + k32];
            if (bi > 0) {
                #pragma unroll
                for (int t = 0; t < BT; ++t)
                    dvp[t] = dv_s[pv][t * KK + k32];
            } else {
                #pragma unroll
                for (int t = 0; t < BT; ++t) dvp[t] = 0.f;
            }
            float vo = V_c[s0 * KK + k32];
            #pragma unroll
            for (int u = 0; u < BT; ++u) {
                int s = s0 + u;
                float von = (u + 1 < BT) ? V_c[(s + 1) * KK + k32] : 0.f;
                // fold: g[u] += cmini[pv][u][t] * dv(bi-1)[t]  (off-chain FMAs)
                #pragma unroll
                for (int t = 0; t < BT; ++t)
                    g[u] = fmaf(cmini_s[pv][u * BT + t], dvp[t], g[u]);
                float n2 = g[u] * g[u];
                n2 = rowsum16(n2);
                n2 += __shfl_xor(n2, 16, 32);
                float inv = -__builtin_amdgcn_rsqf(fmaxf(n2, 1e-16f));
                float msk = (s < nA) ? 1.f : 0.f;
                float d = fmaf(g[u], inv, -vo) * msk;
                if (tid < 32) {
                    dv_s[cb][u * KK + k32] = d;
                    V_c[s * KK + k32] = vo + d;
                }
                #pragma unroll
                for (int u2 = u + 1; u2 < BT; ++u2)
                    g[u2] = fmaf(cblk_s[cb][u * BT + u2], d, g[u2]);
                vo = von;
            }
            __builtin_amdgcn_s_setprio(0);
        } else {
            // staging (scalar gathers from Ct via act_s; off critical path)
            if (wid == 6) {   // cmini[cb][u*16+t] = C[r_{s0+t}][r_{sn0+u}]  (for bi+1's fold)
                for (int idx = l64; idx < BT * BT; idx += 64) {
                    int u = idx >> 4, t = idx & 15;
                    cmini_s[cb][u * BT + t] =
                        Ct_g[(size_t)act_s[sn0 + u] * NF + act_s[s0 + t]];
                }
            }
            if (wid == 7) {   // cblk[pv][x*16+y] = C[r_{sn0+x}][r_{sn0+y}] = Ct[r_y][r_x]
                for (int idx = l64; idx < BT * BT; idx += 64) {
                    int x = idx >> 4, y = idx & 15;
                    cblk_s[pv][idx] =
                        Ct_g[(size_t)act_s[sn0 + y] * NF + act_s[sn0 + x]];
                }
            }
            // ---- bulk: rank-16 via MFMA (A,B bf16; acc fp32) ----
            if (bi > 0) {
                v8s bf0, bf1;
                #pragma unroll
                for (int i = 0; i < 8; ++i) { bf0[i] = 0; bf1[i] = 0; }
                if (l64 < 32) {   // k = rg*8+i in 0..15 real; lanes 32..63 zero-pad
                    #pragma unroll
                    for (int i = 0; i < 8; ++i) {
                        int t = rg * 8 + i;
                        bf0[i] = (short)f2bf(dv_s[pv][t * KK + col]);
                        bf1[i] = (short)f2bf(dv_s[pv][t * KK + 16 + col]);
                    }
                }
                #pragma unroll
                for (int tl = 0; tl < 4; ++tl) {
                    int mt = (wid - 1) * 4 + tl;
                    v8s af;
                    #pragma unroll
                    for (int i = 0; i < 8; ++i) af[i] = 0;
                    if (l64 < 32)
                        af = Apack[((size_t)pblk * NMT + mt) * 32 + l64];
                    acc[tl][0] = __builtin_amdgcn_mfma_f32_16x16x32_bf16(af, bf0, acc[tl][0], 0, 0, 0);
                    acc[tl][1] = __builtin_amdgcn_mfma_f32_16x16x32_bf16(af, bf1, acc[tl][1], 0, 0, 0);
                }
                // diag self-cancel for rows of the previous block (fp32 exact)
                #pragma unroll
                for (int tl = 0; tl < 4; ++tl) {
                    if ((wid - 1) * 4 + tl == pblk) {
                        #pragma unroll
                        for (int i = 0; i < 4; ++i) {
                            int r = rg * 4 + i;
                            float cd = Cd_s[sp0 + r];
                            acc[tl][0][i] = fmaf(-cd, dv_s[pv][r * KK + col],      acc[tl][0][i]);
                            acc[tl][1][i] = fmaf(-cd, dv_s[pv][r * KK + 16 + col], acc[tl][1][i]);
                        }
                    }
                }
            }
            // ---- publish next block's raw rows (fold happens on wave 0) ----
            #pragma unroll
            for (int tl = 0; tl < 4; ++tl) {
                if ((wid - 1) * 4 + tl == nblk2) {
                    #pragma unroll
                    for (int i = 0; i < 4; ++i) {
                        gpub[cb][(rg * 4 + i) * KK + col]      = acc[tl][0][i];
                        gpub[cb][(rg * 4 + i) * KK + 16 + col] = acc[tl][1][i];
                    }
                }
            }
        }
        __syncthreads();
    }

    // ---- epilogue: z_out ----
    int k = tid & 31, r = tid >> 5;   // r in 0..15
    float v0k = Vg[(size_t)b * NF * KK + k];
    for (int n = 1 + r; n <= NN; n += 16) {
        int ii = is_input[b * NN + n - 1];
        float res;
        if (ii == 1) {
            res = z[b * NN + n - 1];
        } else {
            int a = slot_s[n];
            float dot = V_c[a * KK + k] * v0k;
            #pragma unroll
            for (int off = 16; off; off >>= 1) dot += __shfl_xor(dot, off, 32);
            float ca = fminf(fmaxf(-dot, -1.f + 1e-6f), 1.f - 1e-6f);
            res = acosf(ca) * (1.f / PI_F);
        }
        if (k == 0) out[b * NN + n - 1] = res;
    }
}

extern "C" void kernel_launch(void* const* d_in, const int* in_sizes, int n_in,
                              void* d_out, int out_size, void* d_ws, size_t ws_size,
                              hipStream_t stream) {
    const float* coeff    = (const float*)d_in[0];
    const float* upper    = (const float*)d_in[1];
    const float* basis    = (const float*)d_in[2];
    const float* z        = (const float*)d_in[3];
    const int*   is_input = (const int*)d_in[4];
    const float* vraw     = (const float*)d_in[5];
    const int*   perm     = (const int*)d_in[6];
    float* out = (float*)d_out;

    float* ws   = (float*)d_ws;
    float* Ct   = ws;                              // 730*730
    float* V    = Ct + (size_t)NF * NF;            // 8*730*32
    float* Wc   = V + (size_t)BV * NF * KK;        // 8*448*32
    float* Vact = Wc + (size_t)BV * AST * KK;      // 8*448*32
    int*   act  = (int*)(Vact + (size_t)BV * AST * KK);  // 8*448
    int*   nAa  = act + BV * AST;                  // 8
    v8s*  Apack = (v8s*)(nAa + 8);                 // 8*28*28*32 v8s = 3.2 MB
    // total ws ≈ 7.1 MB

    build_C_kernel<<<dim3((NF * NF + 255) / 256), dim3(256), 0, stream>>>(coeff, upper, basis, Ct);
    init_V_kernel<<<dim3(730), dim3(256), 0, stream>>>(z, vraw, V);
    build_act_kernel<<<dim3(BV), dim3(64), 0, stream>>>(is_input, perm, act, nAa);
    init_W_kernel<<<dim3(AST / 8, BV), dim3(256), 0, stream>>>(Ct, act, nAa, V, Wc, Vact);
    prepack_A_kernel<<<dim3(NMT * NMT, BV), dim3(64), 0, stream>>>(Ct, act, Apack);
    mix_kernel<<<dim3(BV), dim3(MTH), 0, stream>>>(Apack, Ct, Wc, Vact, act, nAa, is_input, z, V, out);
}

// Round 23
// 721.857 us; speedup vs baseline: 1.8873x; 1.2415x over previous
//
#include <hip/hip_runtime.h>

#define NN   729
#define NF   730   // N+1
#define BV   8
#define KK   32
#define NBAS 40
#define MAXIT 10
#define PI_F 3.14159265358979323846f

#define MTH   512   // mix threads (8 waves)
#define BT    16    // steps per block
#define AST   448   // padded max active rows
#define NMT   28    // m-tiles (448/16)

typedef short v8s __attribute__((ext_vector_type(8)));
typedef float v4f __attribute__((ext_vector_type(4)));

__device__ __forceinline__ unsigned short f2bf(float f) {
    unsigned int x = __float_as_uint(f);
    unsigned int r = x + 0x7FFFu + ((x >> 16) & 1u);   // RNE bf16
    return (unsigned short)(r >> 16);
}

// ---------------- build Ct (730x730), Ct[i][j] = C[j][i] ----------------
__global__ void build_C_kernel(const float* __restrict__ coeff,
                               const float* __restrict__ upper,
                               const float* __restrict__ basis,
                               float* __restrict__ Ct) {
    int idx = blockIdx.x * blockDim.x + threadIdx.x;
    if (idx >= NF * NF) return;
    int i = idx / NF, j = idx - i * NF;
    float val;
    if (i == 0) {
        val = (j == 0) ? 0.f : upper[j - 1];
    } else if (j == 0) {
        val = upper[i - 1];
    } else {
        float acc = 0.f;
        const float* bp = basis + (size_t)(i - 1) * NN + (j - 1);
        #pragma unroll 8
        for (int b = 0; b < NBAS; ++b)
            acc = fmaf(coeff[b], bp[(size_t)b * NN * NN], acc);
        val = acc;
    }
    Ct[(size_t)j * NF + i] = val;
}

// ---------------- init V  (B x 730 x 32) ----------------
__global__ void init_V_kernel(const float* __restrict__ z,
                              const float* __restrict__ vraw,
                              float* __restrict__ V) {
    int g = threadIdx.x >> 5;
    int k = threadIdx.x & 31;
    int row = blockIdx.x * 8 + g;           // 0..5839
    int b = row / NF, n = row - b * NF;
    const float* vr = vraw + (size_t)b * NF * KK;

    float v0 = vr[k];
    float s2 = v0 * v0;
    #pragma unroll
    for (int off = 16; off; off >>= 1) s2 += __shfl_xor(s2, off, 32);
    v0 = v0 / sqrtf(s2);

    float vn = vr[(size_t)n * KK + k];
    float d = vn * v0;
    #pragma unroll
    for (int off = 16; off; off >>= 1) d += __shfl_xor(d, off, 32);
    float u = vn - d * v0;
    float un2 = u * u;
    #pragma unroll
    for (int off = 16; off; off >>= 1) un2 += __shfl_xor(un2, off, 32);
    u = u / fmaxf(sqrtf(un2), 1e-8f);

    float zf = (n == 0) ? 1.f : z[b * NN + (n - 1)];
    float c = cosf(PI_F * zf), s = sinf(PI_F * zf);
    float outv = -c * v0 + s * u;
    if (n == 0) outv = v0;
    V[((size_t)b * NF + n) * KK + k] = outv;
}

// ---------------- build per-batch active lists (perm order) ----------------
__global__ void build_act_kernel(const int* __restrict__ is_input,
                                 const int* __restrict__ perm,
                                 int* __restrict__ act, int* __restrict__ nA_arr) {
    int b = blockIdx.x, l = threadIdx.x;   // 64 threads = 1 wave
    int base = 0;
    for (int c = 0; c < (NN + 63) / 64; ++c) {
        int idx = c * 64 + l;
        bool f = false; int pi = 0;
        if (idx < NN) { pi = perm[idx]; f = (is_input[b * NN + pi - 1] == 0); }
        unsigned long long m = __ballot(f);
        int pos = __popcll(m & ((1ull << l) - 1ull));
        if (f && base + pos < AST) act[b * AST + base + pos] = pi;
        base += __popcll(m);
    }
    if (base > AST) base = AST;
    if (l == 0) nA_arr[b] = base;
    for (int p = base + l; p < AST; p += 64) act[b * AST + p] = 0;
}

// --- init W compact + compact V copy ---
__global__ void init_W_kernel(const float* __restrict__ Ct,
                              const int* __restrict__ act,
                              const int* __restrict__ nA_arr,
                              const float* __restrict__ V,
                              float* __restrict__ Wc,
                              float* __restrict__ Vact) {
    int b = blockIdx.y;
    int a = blockIdx.x * 8 + (threadIdx.x >> 5);
    int k = threadIdx.x & 31;
    int nA = nA_arr[b];
    float w = 0.f;
    int ra = act[b * AST + a];
    float vv = V[((size_t)b * NF + ra) * KK + k];
    if (a < nA) {
        const float* ctr = Ct + (size_t)ra * NF;
        const float* vb = V + (size_t)b * NF * KK + k;
        float acc = 0.f;
        for (int j = 0; j < NF; ++j)
            acc = fmaf(ctr[j], vb[(size_t)j * KK], acc);
        w = acc - ctr[ra] * vv;
    }
    Wc[((size_t)b * AST + a) * KK + k] = w;
    Vact[((size_t)b * AST + a) * KK + k] = vv;
}

// --- prepack A fragments (bf16): A[row][t] = C[r_{pb*16+t}][r_{mt*16+row}]
//     = Ct[r_row][r_t]. Fragment: lane l (0..31): row=l&15, k=(l>>4)*8+i. ---
__global__ void prepack_A_kernel(const float* __restrict__ Ct,
                                 const int* __restrict__ act,
                                 v8s* __restrict__ Apack) {
    int b = blockIdx.y, pm = blockIdx.x;      // pm = pb*NMT + mt
    int pb = pm / NMT, mt = pm - NMT * pb;
    int l = threadIdx.x;                      // 64
    if (l >= 32) return;
    int row = mt * 16 + (l & 15);
    int ra = act[b * AST + row];
    const float* crow = Ct + (size_t)ra * NF;
    v8s v;
    #pragma unroll
    for (int i = 0; i < 8; ++i) {
        int t = (l >> 4) * 8 + i;             // 0..15 (l>>4 in {0,1})
        int rt = act[b * AST + pb * 16 + t];
        v[i] = (short)f2bf(crow[rt]);
    }
    Apack[(((size_t)b * NMT + pb) * NMT + mt) * 32 + l] = v;
}

// 16-lane row sum via DPP row rotations (pure VALU)
__device__ __forceinline__ float rowsum16(float x) {
    int y;
    y = __builtin_amdgcn_update_dpp(0, __float_as_int(x), 0x121, 0xF, 0xF, false);
    x += __int_as_float(y);
    y = __builtin_amdgcn_update_dpp(0, __float_as_int(x), 0x122, 0xF, 0xF, false);
    x += __int_as_float(y);
    y = __builtin_amdgcn_update_dpp(0, __float_as_int(x), 0x124, 0xF, 0xF, false);
    x += __int_as_float(y);
    y = __builtin_amdgcn_update_dpp(0, __float_as_int(x), 0x128, 0xF, 0xF, false);
    x += __int_as_float(y);
    return x;
}

// -- mixing: bulk = MFMA rank-16 (bf16 A/B, fp32 acc); serial + fold fp32 --
__global__ __launch_bounds__(MTH, 2)
void mix_kernel(const v8s* __restrict__ Apack_g,
                const float* __restrict__ Ct_g,
                const float* __restrict__ Wc_g,
                const float* __restrict__ Vact_g,
                const int* __restrict__ act_g,
                const int* __restrict__ nA_arr,
                const int* __restrict__ is_input,
                const float* __restrict__ z,
                const float* __restrict__ Vg,
                float* __restrict__ out) {
    __shared__ __align__(16) float V_c[AST * KK];       // 57344 B
    __shared__ __align__(16) float dv_s[2][BT * KK];    // 4096 B
    __shared__ __align__(16) float gpub[2][BT * KK];    // 4096 B
    __shared__ __align__(16) float cblk_s[2][BT * BT];  // 2048 B
    __shared__ __align__(16) float cmini_s[BT * BT];    // 1024 B
    __shared__ float Cd_s[AST];                         // 1792 B
    __shared__ int   slot_s[NF];                        // 2920 B
    __shared__ int   act_s[AST];                        // 1792 B

    int b = blockIdx.x, tid = threadIdx.x;
    const v8s* Apack = Apack_g + ((size_t)b * NMT * NMT) * 32;
    const float* Vact = Vact_g + (size_t)b * AST * KK;
    int nA = nA_arr[b];
    int nblkp = (nA + BT - 1) / BT;
    if (nblkp < 2) nblkp = 2;
    if (nblkp > NMT) nblkp = NMT;
    int totB = MAXIT * nblkp;

    int wid = tid >> 6;
    int l64 = tid & 63;
    int col = l64 & 15, rg = l64 >> 4;    // MFMA fragment coords
    int k32 = tid & 31;                   // serial k

    // ---- setup ----
    if (tid < AST) act_s[tid] = act_g[b * AST + tid];
    __syncthreads();
    for (int idx = tid; idx < AST * 8; idx += MTH)
        ((float4*)V_c)[idx] = ((const float4*)Vact)[idx];
    if (tid < AST) Cd_s[tid] = Ct_g[(size_t)act_s[tid] * NF + act_s[tid]];
    if (tid < nA) slot_s[act_s[tid]] = tid;
    if (tid < 256) {   // cblk for block 0: cblk[t*16+u] = C[r_t][r_u] = Ct[r_u][r_t]
        int t = tid >> 4, u = tid & 15;
        cblk_s[0][t * BT + u] = Ct_g[(size_t)act_s[u] * NF + act_s[t]];
    }
    // W accumulators in MFMA C/D layout: acc[tl][nt][i] = W[mt*16+rg*4+i][nt*16+col]
    v4f acc[4][2];
    #pragma unroll
    for (int tl = 0; tl < 4; ++tl)
        #pragma unroll
        for (int nt = 0; nt < 2; ++nt) {
            v4f z4 = {0.f, 0.f, 0.f, 0.f};
            acc[tl][nt] = z4;
        }
    if (wid >= 1) {
        #pragma unroll
        for (int tl = 0; tl < 4; ++tl) {
            int mt = (wid - 1) * 4 + tl;
            #pragma unroll
            for (int nt = 0; nt < 2; ++nt)
                #pragma unroll
                for (int i = 0; i < 4; ++i)
                    acc[tl][nt][i] =
                        Wc_g[((size_t)b * AST + mt * 16 + rg * 4 + i) * KK + nt * 16 + col];
        }
        if (wid == 1) {   // publish tile 0 raw into gpub[1] (pv at bi=0)
            #pragma unroll
            for (int nt = 0; nt < 2; ++nt)
                #pragma unroll
                for (int i = 0; i < 4; ++i)
                    gpub[1][(rg * 4 + i) * KK + nt * 16 + col] = acc[0][nt][i];
        }
    }
    __syncthreads();

    for (int bi = 0; bi < totB; ++bi) {
        int blk = bi % nblkp, s0 = blk * BT;
        int pblk = (bi - 1 + nblkp) % nblkp, sp0 = pblk * BT;  // junk at bi=0
        int cb = bi & 1, pv = cb ^ 1;
        int nblk2 = (bi + 1) % nblkp, sn0 = nblk2 * BT;

        // ================= Region 1 =================
        if (wid == 0) {
            // ---- serial: 16-step chain, 1 float/lane ----
            __builtin_amdgcn_s_setprio(1);
            float g[BT], vo[BT];
            #pragma unroll
            for (int u = 0; u < BT; ++u) {
                g[u]  = gpub[pv][u * KK + k32];
                vo[u] = V_c[(s0 + u) * KK + k32];
            }
            #pragma unroll
            for (int u = 0; u < BT; ++u) {
                int s = s0 + u;
                float n2 = g[u] * g[u];
                n2 = rowsum16(n2);
                n2 += __shfl_xor(n2, 16, 32);
                float inv = -__builtin_amdgcn_rsqf(fmaxf(n2, 1e-16f));
                float msk = (s < nA) ? 1.f : 0.f;
                float d = fmaf(g[u], inv, -vo[u]) * msk;
                if (tid < 32) {
                    dv_s[cb][u * KK + k32] = d;
                    V_c[s * KK + k32] = vo[u] + d;
                }
                #pragma unroll
                for (int u2 = u + 1; u2 < BT; ++u2)
                    g[u2] = fmaf(cblk_s[cb][u * BT + u2], d, g[u2]);
            }
            __builtin_amdgcn_s_setprio(0);
        } else {
            // staging (scalar gathers from Ct via act_s; off critical path)
            if (wid == 6) {   // cmini[u*16+t] = C[r_{s0+t}][r_{sn0+u}] = Ct[r_{sn0+u}][r_{s0+t}]
                for (int idx = l64; idx < BT * BT; idx += 64) {
                    int u = idx >> 4, t = idx & 15;
                    cmini_s[u * BT + t] =
                        Ct_g[(size_t)act_s[sn0 + u] * NF + act_s[s0 + t]];
                }
            }
            if (wid == 7) {   // cblk[pv][x*16+y] = C[r_{sn0+x}][r_{sn0+y}] = Ct[r_y][r_x]
                for (int idx = l64; idx < BT * BT; idx += 64) {
                    int x = idx >> 4, y = idx & 15;
                    cblk_s[pv][idx] =
                        Ct_g[(size_t)act_s[sn0 + y] * NF + act_s[sn0 + x]];
                }
            }
            // ---- bulk: rank-16 via MFMA (A,B bf16; acc fp32) ----
            if (bi > 0) {
                v8s bf0, bf1;
                #pragma unroll
                for (int i = 0; i < 8; ++i) { bf0[i] = 0; bf1[i] = 0; }
                if (l64 < 32) {   // k = rg*8+i in 0..15 real; lanes 32..63 zero-pad
                    #pragma unroll
                    for (int i = 0; i < 8; ++i) {
                        int t = rg * 8 + i;
                        bf0[i] = (short)f2bf(dv_s[pv][t * KK + col]);
                        bf1[i] = (short)f2bf(dv_s[pv][t * KK + 16 + col]);
                    }
                }
                #pragma unroll
                for (int tl = 0; tl < 4; ++tl) {
                    int mt = (wid - 1) * 4 + tl;
                    v8s af;
                    #pragma unroll
                    for (int i = 0; i < 8; ++i) af[i] = 0;
                    if (l64 < 32)
                        af = Apack[((size_t)pblk * NMT + mt) * 32 + l64];
                    acc[tl][0] = __builtin_amdgcn_mfma_f32_16x16x32_bf16(af, bf0, acc[tl][0], 0, 0, 0);
                    acc[tl][1] = __builtin_amdgcn_mfma_f32_16x16x32_bf16(af, bf1, acc[tl][1], 0, 0, 0);
                }
                // diag self-cancel for rows of the previous block (fp32 exact)
                #pragma unroll
                for (int tl = 0; tl < 4; ++tl) {
                    if ((wid - 1) * 4 + tl == pblk) {
                        #pragma unroll
                        for (int i = 0; i < 4; ++i) {
                            int r = rg * 4 + i;
                            float cd = Cd_s[sp0 + r];
                            acc[tl][0][i] = fmaf(-cd, dv_s[pv][r * KK + col],      acc[tl][0][i]);
                            acc[tl][1][i] = fmaf(-cd, dv_s[pv][r * KK + 16 + col], acc[tl][1][i]);
                        }
                    }
                }
            }
            // ---- publish next block's raw rows (fold happens in R2) ----
            #pragma unroll
            for (int tl = 0; tl < 4; ++tl) {
                if ((wid - 1) * 4 + tl == nblk2) {
                    #pragma unroll
                    for (int i = 0; i < 4; ++i) {
                        gpub[cb][(rg * 4 + i) * KK + col]      = acc[tl][0][i];
                        gpub[cb][(rg * 4 + i) * KK + 16 + col] = acc[tl][1][i];
                    }
                }
            }
        }
        __syncthreads();

        // ===== Region 2: cooperative fold gpub[cb] += cmini * dv(bi) =====
        {
            int u = tid >> 5, k = tid & 31;
            float g = gpub[cb][u * KK + k];
            #pragma unroll
            for (int t = 0; t < BT; ++t)
                g = fmaf(cmini_s[u * BT + t], dv_s[cb][t * KK + k], g);
            gpub[cb][u * KK + k] = g;
        }
        __syncthreads();
    }

    // ---- epilogue: z_out ----
    int k = tid & 31, r = tid >> 5;   // r in 0..15
    float v0k = Vg[(size_t)b * NF * KK + k];
    for (int n = 1 + r; n <= NN; n += 16) {
        int ii = is_input[b * NN + n - 1];
        float res;
        if (ii == 1) {
            res = z[b * NN + n - 1];
        } else {
            int a = slot_s[n];
            float dot = V_c[a * KK + k] * v0k;
            #pragma unroll
            for (int off = 16; off; off >>= 1) dot += __shfl_xor(dot, off, 32);
            float ca = fminf(fmaxf(-dot, -1.f + 1e-6f), 1.f - 1e-6f);
            res = acosf(ca) * (1.f / PI_F);
        }
        if (k == 0) out[b * NN + n - 1] = res;
    }
}

extern "C" void kernel_launch(void* const* d_in, const int* in_sizes, int n_in,
                              void* d_out, int out_size, void* d_ws, size_t ws_size,
                              hipStream_t stream) {
    const float* coeff    = (const float*)d_in[0];
    const float* upper    = (const float*)d_in[1];
    const float* basis    = (const float*)d_in[2];
    const float* z        = (const float*)d_in[3];
    const int*   is_input = (const int*)d_in[4];
    const float* vraw     = (const float*)d_in[5];
    const int*   perm     = (const int*)d_in[6];
    float* out = (float*)d_out;

    float* ws   = (float*)d_ws;
    float* Ct   = ws;                              // 730*730
    float* V    = Ct + (size_t)NF * NF;            // 8*730*32
    float* Wc   = V + (size_t)BV * NF * KK;        // 8*448*32
    float* Vact = Wc + (size_t)BV * AST * KK;      // 8*448*32
    int*   act  = (int*)(Vact + (size_t)BV * AST * KK);  // 8*448
    int*   nAa  = act + BV * AST;                  // 8
    v8s*  Apack = (v8s*)(nAa + 8);                 // 8*28*28*32 v8s = 3.2 MB
    // total ws ≈ 7.1 MB

    build_C_kernel<<<dim3((NF * NF + 255) / 256), dim3(256), 0, stream>>>(coeff, upper, basis, Ct);
    init_V_kernel<<<dim3(730), dim3(256), 0, stream>>>(z, vraw, V);
    build_act_kernel<<<dim3(BV), dim3(64), 0, stream>>>(is_input, perm, act, nAa);
    init_W_kernel<<<dim3(AST / 8, BV), dim3(256), 0, stream>>>(Ct, act, nAa, V, Wc, Vact);
    prepack_A_kernel<<<dim3(NMT * NMT, BV), dim3(64), 0, stream>>>(Ct, act, Apack);
    mix_kernel<<<dim3(BV), dim3(MTH), 0, stream>>>(Apack, Ct, Wc, Vact, act, nAa, is_input, z, V, out);
}